// Round 1
// 1941.938 us; speedup vs baseline: 3.1440x; 3.1440x over previous
//
#include <hip/hip_runtime.h>
#include <hip/hip_bf16.h>

using short8  = __attribute__((ext_vector_type(8))) short;
using floatx4 = __attribute__((ext_vector_type(4))) float;
using u16     = unsigned short;

#define NBATCH   4
#define SEQ      4096
#define DMODEL   1024
#define BR       32
#define BC       64
#define NTHREADS 512
#define SCALE    0.03125f   // 1/sqrt(1024)

__device__ __forceinline__ u16 f2bf(float x) {
  union { __hip_bfloat16 h; u16 u; } cv;
  cv.h = __float2bfloat16(x);
  return cv.u;
}

__global__ __launch_bounds__(NTHREADS, 2)
void fa_fwd(const float* __restrict__ Qg,
            const float* __restrict__ Kg,
            const float* __restrict__ Vg,
            float* __restrict__ Og) {
  // sQ holds the FULL 32x1024 Q tile in bf16, converted once in the prologue
  // (previously re-staged from global + re-converted every kt iteration).
  // Row stride 1032 u16 = 516 dwords -> 4-bank shift/row: rows r and r+8
  // alias (2-way, free on CDNA4); 1032 % 8 == 0 keeps 16B alignment.
  __shared__ __align__(16) u16   sQ[32][1032];  // 64.5 KB
  __shared__ __align__(16) u16   sK[64][264];   // 33.8 KB, K d-chunk (256 cols)
  __shared__ __align__(16) float sS[32][66];    // fp32 score tile (32x64)
  __shared__ __align__(16) u16   sP[32][72];    // bf16 softmax weights
  __shared__ float sM[32], sL[32], sAl[32];     // online-softmax state

  const int tid   = threadIdx.x;
  const int w     = tid >> 6;       // wave 0..7
  const int lane  = tid & 63;
  const int quad  = lane >> 4;
  const int l15   = lane & 15;
  const int batch = blockIdx.y;
  const int q0    = blockIdx.x * BR;

  const size_t qbase  = (size_t)(batch * SEQ + q0) * DMODEL;
  const size_t kvbase = (size_t)batch * SEQ * DMODEL;

  if (tid < 32) { sM[tid] = -1e30f; sL[tid] = 0.0f; }

  // ---------------- Q prologue: 32x1024 f32 -> bf16 LDS, ONCE ----------------
  #pragma unroll
  for (int i = 0; i < 16; i++) {              // 8192 float4 / 512 threads
    const int e   = tid + i * NTHREADS;
    const int row = e >> 8;                   // 256 float4 per row
    const int c4  = (e & 255) << 2;
    float4 v = *(const float4*)&Qg[qbase + (size_t)row * DMODEL + c4];
    ushort4 pk = { f2bf(v.x), f2bf(v.y), f2bf(v.z), f2bf(v.w) };
    *(ushort4*)&sQ[row][c4] = pk;
  }

  // O accumulator: wave w owns rows 0..31, col tiles t = 8*ci + w (16 cols each).
  // ALL indexing into acc below is compile-time constant (full unroll) so the
  // array stays in VGPRs. (Previous version: "#pragma unroll 4" left a rolled
  // outer loop -> runtime index -> acc spilled to scratch: VGPR_Count=68,
  // WRITE_SIZE 11 GB of spill traffic, 6.1 ms.)
  floatx4 acc[2][8];
  #pragma unroll
  for (int rt = 0; rt < 2; rt++)
    #pragma unroll
    for (int ci = 0; ci < 8; ci++)
      acc[rt][ci] = (floatx4)0.0f;

  const int wr = w >> 2, wc = w & 3;   // phase-A tile: rows 16*wr, cols 16*wc

  for (int kt = 0; kt < SEQ / BC; kt++) {
    // ================= Phase A: S = Q K^T (32x64), k over D=1024 =================
    floatx4 sacc = (floatx4)0.0f;
    for (int dc = 0; dc < 4; dc++) {
      __syncthreads();   // protect previous chunk's fragment reads (and sQ/sP/sS reuse)
      #pragma unroll
      for (int i = 0; i < 8; i++) {          // K chunk: 64x256 f32 = 4096 float4
        const int e   = tid + i * NTHREADS;
        const int row = e >> 6;
        const int c4  = (e & 63) << 2;
        float4 v = *(const float4*)&Kg[kvbase + (size_t)(kt * BC + row) * DMODEL + dc * 256 + c4];
        ushort4 pk = { f2bf(v.x), f2bf(v.y), f2bf(v.z), f2bf(v.w) };
        *(ushort4*)&sK[row][c4] = pk;
      }
      __syncthreads();
      #pragma unroll
      for (int ks = 0; ks < 8; ks++) {
        // A: lane holds Q[m=l15][k=quad*8+j]; B: lane holds K[n=l15][k=quad*8+j]
        short8 av = *(const short8*)&sQ[wr * 16 + l15][dc * 256 + ks * 32 + quad * 8];
        short8 bv = *(const short8*)&sK[wc * 16 + l15][ks * 32 + quad * 8];
        sacc = __builtin_amdgcn_mfma_f32_16x16x32_bf16(av, bv, sacc, 0, 0, 0);
      }
    }
    // C/D layout: col = l15, row = quad*4 + r
    #pragma unroll
    for (int r = 0; r < 4; r++)
      sS[wr * 16 + quad * 4 + r][wc * 16 + l15] = sacc[r];
    __syncthreads();

    // ================= Phase B: online softmax (16 threads per row) =================
    {
      const int row = tid >> 4;
      const int c0  = tid & 15;
      float v0 = sS[row][c0     ] * SCALE;
      float v1 = sS[row][c0 + 16] * SCALE;
      float v2 = sS[row][c0 + 32] * SCALE;
      float v3 = sS[row][c0 + 48] * SCALE;
      float mx = fmaxf(fmaxf(v0, v1), fmaxf(v2, v3));
      #pragma unroll
      for (int off = 8; off >= 1; off >>= 1)
        mx = fmaxf(mx, __shfl_xor(mx, off, 16));
      const float m_old = sM[row];
      const float m_new = fmaxf(m_old, mx);
      const float p0 = __expf(v0 - m_new);
      const float p1 = __expf(v1 - m_new);
      const float p2 = __expf(v2 - m_new);
      const float p3 = __expf(v3 - m_new);
      sP[row][c0     ] = f2bf(p0);
      sP[row][c0 + 16] = f2bf(p1);
      sP[row][c0 + 32] = f2bf(p2);
      sP[row][c0 + 48] = f2bf(p3);
      float sum = p0 + p1 + p2 + p3;
      #pragma unroll
      for (int off = 8; off >= 1; off >>= 1)
        sum += __shfl_xor(sum, off, 16);
      if (c0 == 0) {
        const float al = __expf(m_old - m_new);   // exp(-1e30 - m) == 0 on first tile
        sAl[row] = al;
        sM[row]  = m_new;
        sL[row]  = sL[row] * al + sum;
      }
    }
    __syncthreads();

    // ================= rescale O by alpha (all indices static) =================
    float alv[2][4];
    #pragma unroll
    for (int rt = 0; rt < 2; rt++)
      #pragma unroll
      for (int r = 0; r < 4; r++)
        alv[rt][r] = sAl[rt * 16 + quad * 4 + r];
    #pragma unroll
    for (int rt = 0; rt < 2; rt++)
      #pragma unroll
      for (int ci = 0; ci < 8; ci++)
        #pragma unroll
        for (int r = 0; r < 4; r++)
          acc[rt][ci][r] *= alv[rt][r];

    // ================= Phase C: O += P V (V B-frags direct from global) =========
    #pragma unroll
    for (int ks = 0; ks < 2; ks++) {
      short8 a0 = *(const short8*)&sP[l15     ][ks * 32 + quad * 8];
      short8 a1 = *(const short8*)&sP[16 + l15][ks * 32 + quad * 8];
      #pragma unroll
      for (int ci = 0; ci < 8; ci++) {       // FULL unroll: static acc index
        const int col = ((ci << 3) + w) * 16 + l15;      // d column (n = l15)
        const float* vp = Vg + kvbase +
                          (size_t)(kt * BC + ks * 32 + quad * 8) * DMODEL + col;
        short8 bv;    // B: lane holds V[k=quad*8+j][n=col]
        #pragma unroll
        for (int j = 0; j < 8; j++)
          bv[j] = (short)f2bf(vp[(size_t)j * DMODEL]);
        acc[0][ci] = __builtin_amdgcn_mfma_f32_16x16x32_bf16(a0, bv, acc[0][ci], 0, 0, 0);
        acc[1][ci] = __builtin_amdgcn_mfma_f32_16x16x32_bf16(a1, bv, acc[1][ci], 0, 0, 0);
      }
    }
  }

  // ================= epilogue: O /= l, store FLOAT32 (reference output dtype) ==
  float linv[2][4];
  #pragma unroll
  for (int rt = 0; rt < 2; rt++)
    #pragma unroll
    for (int r = 0; r < 4; r++)
      linv[rt][r] = 1.0f / sL[rt * 16 + quad * 4 + r];
  #pragma unroll
  for (int rt = 0; rt < 2; rt++)
    #pragma unroll
    for (int ci = 0; ci < 8; ci++) {
      const int col = ((ci << 3) + w) * 16 + l15;
      #pragma unroll
      for (int r = 0; r < 4; r++) {
        const int row = q0 + rt * 16 + quad * 4 + r;
        Og[(size_t)(batch * SEQ + row) * DMODEL + col] = acc[rt][ci][r] * linv[rt][r];
      }
    }
}

extern "C" void kernel_launch(void* const* d_in, const int* in_sizes, int n_in,
                              void* d_out, int out_size, void* d_ws, size_t ws_size,
                              hipStream_t stream) {
  // Harness contract: inputs in setup_inputs() dict order (query, key, value),
  // f32; output dtype = reference output dtype = float32.
  const float* Q = (const float*)d_in[0];
  const float* K = (const float*)d_in[1];
  const float* V = (const float*)d_in[2];
  float* O = (float*)d_out;
  dim3 grid(SEQ / BR, NBATCH);
  fa_fwd<<<grid, NTHREADS, 0, stream>>>(Q, K, V, O);
}

// Round 2
// 1030.512 us; speedup vs baseline: 5.9248x; 1.8844x over previous
//
#include <hip/hip_runtime.h>
#include <hip/hip_bf16.h>

using short8  = __attribute__((ext_vector_type(8))) short;
using floatx4 = __attribute__((ext_vector_type(4))) float;
using u16     = unsigned short;
using u32     = unsigned int;

#define NBATCH   4
#define SEQ      4096
#define DMODEL   1024
#define BR       32
#define BC       64
#define NTHREADS 512
#define SCALE    0.03125f   // 1/sqrt(1024)
#define NKT      (SEQ / BC) // 64 kv-tiles

__device__ __forceinline__ u16 f2bf(float x) {
  union { __hip_bfloat16 h; u16 u; } cv;
  cv.h = __float2bfloat16(x);
  return cv.u;
}

// async global->LDS, 16B per lane. LDS dest = wave-uniform base + lane*16.
__device__ __forceinline__ void gload16(const void* g, void* l) {
  __builtin_amdgcn_global_load_lds(
      (const __attribute__((address_space(1))) u32*)g,
      (__attribute__((address_space(3))) u32*)l, 16, 0, 0);
}

// ============================ pre-pass kernels ==============================
// Kws layout: per (b, kt, dc) a contiguous 32KB chunk = [64 rows][256 cols] bf16,
// pre-scaled by SCALE, cols XOR-swizzled within each row: c' = c ^ ((s&7)<<3)
// (element-granularity form of the byte swizzle ((row&7)<<4)).
__global__ __launch_bounds__(256)
void conv_k(const float* __restrict__ Kg, u16* __restrict__ Kws) {
  const int s = blockIdx.x, b = blockIdx.y, t = threadIdx.x;
  const int c4 = t << 2;
  float4 v = *(const float4*)&Kg[((size_t)(b * SEQ + s)) * DMODEL + c4];
  ushort4 pk = { f2bf(v.x * SCALE), f2bf(v.y * SCALE),
                 f2bf(v.z * SCALE), f2bf(v.w * SCALE) };
  const int dc = c4 >> 8;
  const int cl = (c4 & 255) ^ ((s & 7) << 3);   // c4%8 in {0,4}: no block straddle
  const size_t chunk = (size_t)(b * NKT + (s >> 6)) * 4 + dc;
  *(ushort4*)&Kws[chunk * 16384 + (size_t)(s & 63) * 256 + cl] = pk;
}

// Vws layout: [b][kt][d(0..1023)][k(0..63)] bf16 (block-transposed), k-index
// XOR-swizzled: k' = k ^ ((d&7)<<3). Each (b,kt,dc) chunk = contiguous 32KB.
__global__ __launch_bounds__(256)
void conv_v(const float* __restrict__ Vg, u16* __restrict__ Vws) {
  __shared__ u16 sT[64][68];
  const int ktile = blockIdx.x, dt = blockIdx.y, b = blockIdx.z;
  const int tid = threadIdx.x;
  const int s0 = ktile * 64, d0 = dt * 64;
  #pragma unroll
  for (int i = 0; i < 4; i++) {
    const int e = tid + i * 256;
    const int r = e >> 4, c4 = (e & 15) << 2;
    float4 v = *(const float4*)&Vg[((size_t)(b * SEQ + s0 + r)) * DMODEL + d0 + c4];
    ushort4 pk = { f2bf(v.x), f2bf(v.y), f2bf(v.z), f2bf(v.w) };
    *(ushort4*)&sT[r][c4] = pk;
  }
  __syncthreads();
  #pragma unroll
  for (int i = 0; i < 4; i++) {
    const int e = tid + i * 256;
    const int dr = e >> 4, s4 = (e & 15) << 2;
    ushort4 pk;
    pk.x = sT[s4 + 0][dr]; pk.y = sT[s4 + 1][dr];
    pk.z = sT[s4 + 2][dr]; pk.w = sT[s4 + 3][dr];
    const int s4s = s4 ^ ((dr & 7) << 3);
    *(ushort4*)&Vws[((size_t)((b * NKT + ktile) * 1024 + d0 + dr)) * 64 + s4s] = pk;
  }
}

// ============================== main kernel =================================
__global__ __launch_bounds__(NTHREADS, 2)
void fa_fwd2(const float* __restrict__ Qg,
             const u16* __restrict__ Kws,
             const u16* __restrict__ Vws,
             float* __restrict__ Og) {
  // sQ: 32x1024 bf16, LINEAR rows (2048B), cols XOR-swizzled by ((row&7)<<3).
  // sU: two 32KB staging buffers, alternating K-chunk / V-chunk views.
  __shared__ __align__(16) u16   sQ[32 * 1024];   // 64 KB
  __shared__ __align__(16) u16   sU[2][16384];    // 2 x 32 KB
  __shared__ __align__(16) float sS[32][66];
  __shared__ __align__(16) u16   sP[32][72];
  __shared__ float sM[32], sL[32], sAl[32];

  const int tid   = threadIdx.x;
  const int w     = tid >> 6;
  const int lane  = tid & 63;
  const int quad  = lane >> 4;
  const int l15   = lane & 15;
  const int batch = blockIdx.y;
  const int q0    = blockIdx.x * BR;

  if (tid < 32) { sM[tid] = -1e30f; sL[tid] = 0.0f; }

  // ---- Q prologue: f32 -> bf16, swizzled ds_writes, ONCE ----
  const size_t qbase = (size_t)(batch * SEQ + q0) * DMODEL;
  #pragma unroll
  for (int i = 0; i < 16; i++) {
    const int e   = tid + i * NTHREADS;
    const int row = e >> 8;
    const int c4  = (e & 255) << 2;
    float4 v = *(const float4*)&Qg[qbase + (size_t)row * DMODEL + c4];
    ushort4 pk = { f2bf(v.x), f2bf(v.y), f2bf(v.z), f2bf(v.w) };
    *(ushort4*)&sQ[row * 1024 + (c4 ^ ((row & 7) << 3))] = pk;
  }

  const char* KB = (const char*)Kws + (size_t)batch * NKT * 4 * 32768;
  const char* VB = (const char*)Vws + (size_t)batch * NKT * 131072;

  // stage one 32KB chunk: 4 x global_load_lds dwordx4 per thread, linear LDS
  #define STAGE32K(gbase, ubuf) do {                                        \
    const char* g_ = (gbase);                                               \
    char* lb_ = (char*)&(ubuf)[0] + ((tid & ~63) << 4);                     \
    const int lo_ = tid << 4;                                               \
    gload16(g_ + lo_,          lb_);                                        \
    gload16(g_ + lo_ +  8192,  lb_ +  8192);                                \
    gload16(g_ + lo_ + 16384,  lb_ + 16384);                                \
    gload16(g_ + lo_ + 24576,  lb_ + 24576);                                \
  } while (0)

  floatx4 acc[2][8];
  #pragma unroll
  for (int rt = 0; rt < 2; rt++)
    #pragma unroll
    for (int ci = 0; ci < 8; ci++)
      acc[rt][ci] = (floatx4)0.0f;

  const int wr = w >> 2, wc = w & 3;
  const int qrow = wr * 16 + l15;
  const u32 qro  = qrow * 2048;            // byte row base in sQ
  const u32 qxor = (qrow & 7) << 4;        // byte swizzle
  const int krow = wc * 16 + l15;
  const u32 kro  = krow * 512;             // byte row base in K chunk
  const u32 kxor = (krow & 7) << 4;

  // prologue: stage K(kt=0,dc=0) into sU[0]
  STAGE32K(KB, sU[0]);
  __syncthreads();

  for (int kt = 0; kt < NKT; kt++) {
    // ============ Phase A: S = Q K^T, 4 dc phases, dbuf-prefetched ============
    floatx4 sacc = (floatx4)0.0f;
    #pragma unroll
    for (int dc = 0; dc < 4; dc++) {
      if (dc < 3)
        STAGE32K(KB + (size_t)(kt * 4 + dc + 1) * 32768, sU[(dc + 1) & 1]);
      else
        STAGE32K(VB + (size_t)kt * 131072, sU[0]);   // V chunk 0 for Phase C
      const u16* ub = sU[dc & 1];
      #pragma unroll
      for (int ks = 0; ks < 8; ks++) {
        short8 av = *(const short8*)((const char*)sQ +
                      (qro + ((dc * 512 + ks * 64 + quad * 16) ^ qxor)));
        short8 bv = *(const short8*)((const char*)ub +
                      (kro + ((ks * 64 + quad * 16) ^ kxor)));
        sacc = __builtin_amdgcn_mfma_f32_16x16x32_bf16(av, bv, sacc, 0, 0, 0);
      }
      if (dc == 3) {   // fold sS write into last A phase (pre-barrier)
        #pragma unroll
        for (int r = 0; r < 4; r++)
          sS[wr * 16 + quad * 4 + r][wc * 16 + l15] = sacc[r];
      }
      __syncthreads();
    }

    // ============ Phase B: online softmax (K pre-scaled, no SCALE here) ======
    STAGE32K(VB + (size_t)kt * 131072 + 32768, sU[1]);  // prefetch V chunk 1
    {
      const int row = tid >> 4;
      const int c0  = tid & 15;
      float v0 = sS[row][c0     ];
      float v1 = sS[row][c0 + 16];
      float v2 = sS[row][c0 + 32];
      float v3 = sS[row][c0 + 48];
      float mx = fmaxf(fmaxf(v0, v1), fmaxf(v2, v3));
      #pragma unroll
      for (int off = 8; off >= 1; off >>= 1)
        mx = fmaxf(mx, __shfl_xor(mx, off, 16));
      const float m_old = sM[row];
      const float m_new = fmaxf(m_old, mx);
      const float p0 = __expf(v0 - m_new);
      const float p1 = __expf(v1 - m_new);
      const float p2 = __expf(v2 - m_new);
      const float p3 = __expf(v3 - m_new);
      sP[row][c0     ] = f2bf(p0);
      sP[row][c0 + 16] = f2bf(p1);
      sP[row][c0 + 32] = f2bf(p2);
      sP[row][c0 + 48] = f2bf(p3);
      float sum = p0 + p1 + p2 + p3;
      #pragma unroll
      for (int off = 8; off >= 1; off >>= 1)
        sum += __shfl_xor(sum, off, 16);
      if (c0 == 0) {
        const float al = __expf(m_old - m_new);
        sAl[row] = al;
        sM[row]  = m_new;
        sL[row]  = sL[row] * al + sum;
      }
    }
    __syncthreads();

    // hoist P fragments (constant across the 4 C phases)
    short8 pa[2][2];
    pa[0][0] = *(const short8*)&sP[l15     ][quad * 8];
    pa[0][1] = *(const short8*)&sP[16 + l15][quad * 8];
    pa[1][0] = *(const short8*)&sP[l15     ][32 + quad * 8];
    pa[1][1] = *(const short8*)&sP[16 + l15][32 + quad * 8];

    // rescale O by alpha (static indices)
    float alv[2][4];
    #pragma unroll
    for (int rt = 0; rt < 2; rt++)
      #pragma unroll
      for (int r = 0; r < 4; r++)
        alv[rt][r] = sAl[rt * 16 + quad * 4 + r];
    #pragma unroll
    for (int rt = 0; rt < 2; rt++)
      #pragma unroll
      for (int ci = 0; ci < 8; ci++)
        #pragma unroll
        for (int r = 0; r < 4; r++)
          acc[rt][ci][r] *= alv[rt][r];

    // ============ Phase C: O += P V, 4 dc phases, dbuf-prefetched ============
    #pragma unroll
    for (int dc = 0; dc < 4; dc++) {
      if (dc == 1 || dc == 2)
        STAGE32K(VB + (size_t)kt * 131072 + (size_t)(dc + 1) * 32768,
                 sU[(dc + 1) & 1]);
      else if (dc == 3)   // prefetch next kt's K chunk 0
        STAGE32K(KB + (size_t)(((kt + 1) & (NKT - 1)) * 4) * 32768, sU[0]);
      const u16* ub = sU[dc & 1];
      #pragma unroll
      for (int ks = 0; ks < 2; ks++) {
        #pragma unroll
        for (int cil = 0; cil < 2; cil++) {
          const int ci   = dc * 2 + cil;
          const int colc = (cil * 8 + w) * 16 + l15;
          short8 bv = *(const short8*)((const char*)ub +
                        (colc * 128 + ((ks * 64 + quad * 16) ^ ((colc & 7) << 4))));
          acc[0][ci] = __builtin_amdgcn_mfma_f32_16x16x32_bf16(pa[ks][0], bv, acc[0][ci], 0, 0, 0);
          acc[1][ci] = __builtin_amdgcn_mfma_f32_16x16x32_bf16(pa[ks][1], bv, acc[1][ci], 0, 0, 0);
        }
      }
      __syncthreads();
    }
  }

  // ================= epilogue: O /= l, store f32 =================
  float linv[2][4];
  #pragma unroll
  for (int rt = 0; rt < 2; rt++)
    #pragma unroll
    for (int r = 0; r < 4; r++)
      linv[rt][r] = 1.0f / sL[rt * 16 + quad * 4 + r];
  #pragma unroll
  for (int rt = 0; rt < 2; rt++)
    #pragma unroll
    for (int ci = 0; ci < 8; ci++) {
      const int col = ((ci << 3) + w) * 16 + l15;
      #pragma unroll
      for (int r = 0; r < 4; r++) {
        const int row = q0 + rt * 16 + quad * 4 + r;
        Og[(size_t)(batch * SEQ + row) * DMODEL + col] = acc[rt][ci][r] * linv[rt][r];
      }
    }
  #undef STAGE32K
}

// ===================== fallback (verified round-1 kernel) ====================
__global__ __launch_bounds__(NTHREADS, 2)
void fa_fwd_fb(const float* __restrict__ Qg,
               const float* __restrict__ Kg,
               const float* __restrict__ Vg,
               float* __restrict__ Og) {
  __shared__ __align__(16) u16   sQ[32][1032];
  __shared__ __align__(16) u16   sK[64][264];
  __shared__ __align__(16) float sS[32][66];
  __shared__ __align__(16) u16   sP[32][72];
  __shared__ float sM[32], sL[32], sAl[32];

  const int tid   = threadIdx.x;
  const int w     = tid >> 6;
  const int lane  = tid & 63;
  const int quad  = lane >> 4;
  const int l15   = lane & 15;
  const int batch = blockIdx.y;
  const int q0    = blockIdx.x * BR;

  const size_t qbase  = (size_t)(batch * SEQ + q0) * DMODEL;
  const size_t kvbase = (size_t)batch * SEQ * DMODEL;

  if (tid < 32) { sM[tid] = -1e30f; sL[tid] = 0.0f; }

  #pragma unroll
  for (int i = 0; i < 16; i++) {
    const int e   = tid + i * NTHREADS;
    const int row = e >> 8;
    const int c4  = (e & 255) << 2;
    float4 v = *(const float4*)&Qg[qbase + (size_t)row * DMODEL + c4];
    ushort4 pk = { f2bf(v.x), f2bf(v.y), f2bf(v.z), f2bf(v.w) };
    *(ushort4*)&sQ[row][c4] = pk;
  }

  floatx4 acc[2][8];
  #pragma unroll
  for (int rt = 0; rt < 2; rt++)
    #pragma unroll
    for (int ci = 0; ci < 8; ci++)
      acc[rt][ci] = (floatx4)0.0f;

  const int wr = w >> 2, wc = w & 3;

  for (int kt = 0; kt < SEQ / BC; kt++) {
    floatx4 sacc = (floatx4)0.0f;
    for (int dc = 0; dc < 4; dc++) {
      __syncthreads();
      #pragma unroll
      for (int i = 0; i < 8; i++) {
        const int e   = tid + i * NTHREADS;
        const int row = e >> 6;
        const int c4  = (e & 63) << 2;
        float4 v = *(const float4*)&Kg[kvbase + (size_t)(kt * BC + row) * DMODEL + dc * 256 + c4];
        ushort4 pk = { f2bf(v.x), f2bf(v.y), f2bf(v.z), f2bf(v.w) };
        *(ushort4*)&sK[row][c4] = pk;
      }
      __syncthreads();
      #pragma unroll
      for (int ks = 0; ks < 8; ks++) {
        short8 av = *(const short8*)&sQ[wr * 16 + l15][dc * 256 + ks * 32 + quad * 8];
        short8 bv = *(const short8*)&sK[wc * 16 + l15][ks * 32 + quad * 8];
        sacc = __builtin_amdgcn_mfma_f32_16x16x32_bf16(av, bv, sacc, 0, 0, 0);
      }
    }
    #pragma unroll
    for (int r = 0; r < 4; r++)
      sS[wr * 16 + quad * 4 + r][wc * 16 + l15] = sacc[r];
    __syncthreads();

    {
      const int row = tid >> 4;
      const int c0  = tid & 15;
      float v0 = sS[row][c0     ] * SCALE;
      float v1 = sS[row][c0 + 16] * SCALE;
      float v2 = sS[row][c0 + 32] * SCALE;
      float v3 = sS[row][c0 + 48] * SCALE;
      float mx = fmaxf(fmaxf(v0, v1), fmaxf(v2, v3));
      #pragma unroll
      for (int off = 8; off >= 1; off >>= 1)
        mx = fmaxf(mx, __shfl_xor(mx, off, 16));
      const float m_old = sM[row];
      const float m_new = fmaxf(m_old, mx);
      const float p0 = __expf(v0 - m_new);
      const float p1 = __expf(v1 - m_new);
      const float p2 = __expf(v2 - m_new);
      const float p3 = __expf(v3 - m_new);
      sP[row][c0     ] = f2bf(p0);
      sP[row][c0 + 16] = f2bf(p1);
      sP[row][c0 + 32] = f2bf(p2);
      sP[row][c0 + 48] = f2bf(p3);
      float sum = p0 + p1 + p2 + p3;
      #pragma unroll
      for (int off = 8; off >= 1; off >>= 1)
        sum += __shfl_xor(sum, off, 16);
      if (c0 == 0) {
        const float al = __expf(m_old - m_new);
        sAl[row] = al;
        sM[row]  = m_new;
        sL[row]  = sL[row] * al + sum;
      }
    }
    __syncthreads();

    float alv[2][4];
    #pragma unroll
    for (int rt = 0; rt < 2; rt++)
      #pragma unroll
      for (int r = 0; r < 4; r++)
        alv[rt][r] = sAl[rt * 16 + quad * 4 + r];
    #pragma unroll
    for (int rt = 0; rt < 2; rt++)
      #pragma unroll
      for (int ci = 0; ci < 8; ci++)
        #pragma unroll
        for (int r = 0; r < 4; r++)
          acc[rt][ci][r] *= alv[rt][r];

    #pragma unroll
    for (int ks = 0; ks < 2; ks++) {
      short8 a0 = *(const short8*)&sP[l15     ][ks * 32 + quad * 8];
      short8 a1 = *(const short8*)&sP[16 + l15][ks * 32 + quad * 8];
      #pragma unroll
      for (int ci = 0; ci < 8; ci++) {
        const int col = ((ci << 3) + w) * 16 + l15;
        const float* vp = Vg + kvbase +
                          (size_t)(kt * BC + ks * 32 + quad * 8) * DMODEL + col;
        short8 bv;
        #pragma unroll
        for (int j = 0; j < 8; j++)
          bv[j] = (short)f2bf(vp[(size_t)j * DMODEL]);
        acc[0][ci] = __builtin_amdgcn_mfma_f32_16x16x32_bf16(a0, bv, acc[0][ci], 0, 0, 0);
        acc[1][ci] = __builtin_amdgcn_mfma_f32_16x16x32_bf16(a1, bv, acc[1][ci], 0, 0, 0);
      }
    }
  }

  float linv[2][4];
  #pragma unroll
  for (int rt = 0; rt < 2; rt++)
    #pragma unroll
    for (int r = 0; r < 4; r++)
      linv[rt][r] = 1.0f / sL[rt * 16 + quad * 4 + r];
  #pragma unroll
  for (int rt = 0; rt < 2; rt++)
    #pragma unroll
    for (int ci = 0; ci < 8; ci++) {
      const int col = ((ci << 3) + w) * 16 + l15;
      #pragma unroll
      for (int r = 0; r < 4; r++) {
        const int row = q0 + rt * 16 + quad * 4 + r;
        Og[(size_t)(batch * SEQ + row) * DMODEL + col] = acc[rt][ci][r] * linv[rt][r];
      }
    }
}

extern "C" void kernel_launch(void* const* d_in, const int* in_sizes, int n_in,
                              void* d_out, int out_size, void* d_ws, size_t ws_size,
                              hipStream_t stream) {
  const float* Q = (const float*)d_in[0];
  const float* K = (const float*)d_in[1];
  const float* V = (const float*)d_in[2];
  float* O = (float*)d_out;
  dim3 grid(SEQ / BR, NBATCH);
  const size_t kbytes = (size_t)NBATCH * SEQ * DMODEL * 2;   // 32 MB
  if (ws_size >= 2 * kbytes) {
    u16* Kws = (u16*)d_ws;
    u16* Vws = (u16*)((char*)d_ws + kbytes);
    conv_k<<<dim3(SEQ, NBATCH), 256, 0, stream>>>(K, Kws);
    conv_v<<<dim3(SEQ / 64, DMODEL / 64, NBATCH), 256, 0, stream>>>(V, Vws);
    fa_fwd2<<<grid, NTHREADS, 0, stream>>>(Q, Kws, Vws, O);
  } else {
    fa_fwd_fb<<<grid, NTHREADS, 0, stream>>>(Q, K, V, O);
  }
}